// Round 2
// baseline (314.152 us; speedup 1.0000x reference)
//
#include <hip/hip_runtime.h>
#include <hip/hip_bf16.h>

#define NN 6144
#define HEADS 4
#define DIN 256
#define DOUT 64

typedef __bf16 bf16_t;
typedef bf16_t bf16x8 __attribute__((ext_vector_type(8)));
typedef float f32x16 __attribute__((ext_vector_type(16)));
typedef float f32x4 __attribute__((ext_vector_type(4)));
typedef unsigned u32x4 __attribute__((ext_vector_type(4)));

#if __has_builtin(__builtin_amdgcn_exp2f)
#define EXP2(x) __builtin_amdgcn_exp2f(x)
#else
#define EXP2(x) exp2f(x)
#endif

static __device__ __forceinline__ f32x16 zero16() {
  f32x16 z;
#pragma unroll
  for (int i = 0; i < 16; ++i) z[i] = 0.0f;
  return z;
}

static __device__ __forceinline__ bf16x8 ldg8(const bf16_t* p) {
  return *reinterpret_cast<const bf16x8*>(p);
}

// pack two f32 -> one u32 of 2 bf16 (element 0 in low half)
static __device__ __forceinline__ unsigned pk2(float a, float b) {
  union { bf16_t h[2]; unsigned u; } z;
  z.h[0] = (bf16_t)a;
  z.h[1] = (bf16_t)b;
  return z.u;
}

// v_permlane32_swap_b32: x.hi32lanes <-> y.lo32lanes
static __device__ __forceinline__ void pswap(unsigned& x, unsigned& y) {
  asm("v_permlane32_swap_b32 %0, %1" : "+v"(x), "+v"(y));
}

// ---------------- prep: h -> bf16, W -> transposed bf16 (scale folded into WQ)
__global__ __launch_bounds__(256) void prep_kernel(
    const float* __restrict__ h, const float* __restrict__ WQ,
    const float* __restrict__ WK, const float* __restrict__ WV,
    bf16_t* __restrict__ hb, bf16_t* __restrict__ Wt) {
  int stride = gridDim.x * blockDim.x;
  int idx = blockIdx.x * blockDim.x + threadIdx.x;
  for (int i = idx; i < NN * DIN; i += stride)
    hb[i] = (bf16_t)h[i];
  const float c2 = 0.0625f * 1.4426950408889634f;  // (1/sqrt(256)) * log2(e)
  for (int i = idx; i < 3 * HEADS * DOUT * DIN; i += stride) {
    int d = i & (DIN - 1);
    int o = (i >> 8) & (DOUT - 1);
    int hh = (i >> 14) & (HEADS - 1);
    int m = i >> 16;
    const float* W = (m == 0) ? WQ : (m == 1) ? WK : WV;
    float v = W[(hh * DIN + d) * DOUT + o];
    if (m == 0) v *= c2;
    Wt[i] = (bf16_t)v;  // Wt[m][hh][o][d]
  }
}

// ---------------- proj: Qb,Kb row-major bf16 [H][N][64]; Vt bf16 [H][64][N]
__global__ __launch_bounds__(256) void proj_kernel(
    const bf16_t* __restrict__ hb, const bf16_t* __restrict__ Wt,
    const float* __restrict__ bQ, const float* __restrict__ bK,
    const float* __restrict__ bV,
    bf16_t* __restrict__ Qb, bf16_t* __restrict__ Kb, bf16_t* __restrict__ Vt) {
  const float c2 = 0.0625f * 1.4426950408889634f;
  int tid = threadIdx.x;
  int w = tid >> 6, l = tid & 63;
  int l31 = l & 31, lh = l >> 5;
  int hh = blockIdx.y;
  int n0 = blockIdx.x * 64;

#pragma unroll
  for (int s = 0; s < 3; ++s) {
    int t = w * 3 + s;  // 12 tiles: 0-3 Q, 4-7 K, 8-11 V^T
    if (t < 8) {
      int m = t >> 2;            // 0=Q, 1=K
      int rh = (t >> 1) & 1;     // row half
      int oh = t & 1;            // out-col half
      const bf16_t* arow = hb + (n0 + rh * 32 + l31) * DIN + 8 * lh;
      const bf16_t* brow = Wt + ((m * HEADS + hh) * DOUT + oh * 32 + l31) * DIN + 8 * lh;
      f32x16 acc = zero16();
#pragma unroll
      for (int kc = 0; kc < 16; ++kc)
        acc = __builtin_amdgcn_mfma_f32_32x32x16_bf16(ldg8(arow + kc * 16),
                                                      ldg8(brow + kc * 16), acc, 0, 0, 0);
      const float* bias = (m == 0) ? bQ : bK;
      float bv = bias[hh * DOUT + oh * 32 + l31];
      if (m == 0) bv *= c2;
      bf16_t* outp = ((m == 0) ? Qb : Kb) +
                     (size_t)(hh * NN + n0 + rh * 32) * DOUT + oh * 32 + l31;
#pragma unroll
      for (int r = 0; r < 16; ++r) {
        int q = (r & 3) + 8 * (r >> 2) + 4 * lh;
        outp[q * DOUT] = (bf16_t)(acc[r] + bv);
      }
    } else {
      int tt = t - 8;
      int oh = tt >> 1, nh = tt & 1;
      const bf16_t* arow = Wt + ((2 * HEADS + hh) * DOUT + oh * 32 + l31) * DIN + 8 * lh;
      const bf16_t* brow = hb + (n0 + nh * 32 + l31) * DIN + 8 * lh;
      f32x16 acc = zero16();
#pragma unroll
      for (int kc = 0; kc < 16; ++kc)
        acc = __builtin_amdgcn_mfma_f32_32x32x16_bf16(ldg8(arow + kc * 16),
                                                      ldg8(brow + kc * 16), acc, 0, 0, 0);
      bf16_t* outp = Vt + (size_t)(hh * DOUT + oh * 32) * NN + n0 + nh * 32 + l31;
#pragma unroll
      for (int r = 0; r < 16; ++r) {
        int o = (r & 3) + 8 * (r >> 2) + 4 * lh;
        float bvv = bV[hh * DOUT + oh * 32 + o];
        outp[o * NN] = (bf16_t)(acc[r] + bvv);
      }
    }
  }
}

// ---------------- attention: swapped QK^T, in-register softmax, no P LDS
__global__ __launch_bounds__(256, 2) void attn_kernel(
    const float* __restrict__ adj, const bf16_t* __restrict__ Qb,
    const bf16_t* __restrict__ Kb, const bf16_t* __restrict__ Vt,
    float* __restrict__ out) {
  __shared__ float Opart[4][64][32];  // [wave][d][q]
  __shared__ float Ssum[4][32];

  int tid = threadIdx.x;
  int w = tid >> 6, l = tid & 63;
  int l31 = l & 31, lh = l >> 5;
  int hh = blockIdx.y;
  int q0 = blockIdx.x * 32;

  // Q as B-fragment: col = q = l31, k = kc*16 + 8*lh + 0..7  (pre-scaled by c2)
  const bf16_t* Qrow = Qb + (size_t)(hh * NN + q0 + l31) * DOUT + 8 * lh;
  bf16x8 qf[4];
#pragma unroll
  for (int kc = 0; kc < 4; ++kc) qf[kc] = ldg8(Qrow + kc * 16);

  const bf16_t* Kbase = Kb + (size_t)hh * NN * DOUT;
  const bf16_t* Vbase = Vt + (size_t)hh * DOUT * NN;
  // this thread streams adj row q = q0 + l31; lh selects 16B sub-chunk
  const float* arow = adj + (size_t)hh * NN * NN + (size_t)(q0 + l31) * NN + 4 * lh;

  f32x16 o0 = zero16(), o1 = zero16();
  float sacc = 0.0f;

  for (int it = 0; it < 24; ++it) {
    int key0 = (it * 4 + w) * 64;  // each wave owns disjoint 64-key chunks

    // ---- adj stream: 8 x dwordx4 per lane, issued first (HBM latency hides under QK^T)
    f32x4 av[8];
    const float* ap = arow + key0;
#pragma unroll
    for (int g = 0; g < 4; ++g) {
      av[g]     = *reinterpret_cast<const f32x4*>(ap + 8 * g);        // tile0, keys 8g+4lh+0..3
      av[4 + g] = *reinterpret_cast<const f32x4*>(ap + 32 + 8 * g);   // tile1
    }

    // ---- S^T = K · Q^T : row = key (reg), col = q (lane)
    f32x16 s0 = zero16(), s1 = zero16();
    const bf16_t* krow = Kbase + (size_t)(key0 + l31) * DOUT + 8 * lh;
#pragma unroll
    for (int kc = 0; kc < 4; ++kc) {
      s0 = __builtin_amdgcn_mfma_f32_32x32x16_bf16(ldg8(krow + kc * 16), qf[kc], s0, 0, 0, 0);
      s1 = __builtin_amdgcn_mfma_f32_32x32x16_bf16(ldg8(krow + 32 * DOUT + kc * 16), qf[kc], s1, 0, 0, 0);
    }

    // ---- P = exp2(S^T * adj); pack + permlane32_swap into PV B-frags; PV MFMA
#pragma unroll
    for (int t = 0; t < 2; ++t) {
      f32x16 st = t ? s1 : s0;
      float p[16];
#pragma unroll
      for (int r = 0; r < 16; ++r) {
        float pv = EXP2(st[r] * av[4 * t + (r >> 2)][r & 3]);
        p[r] = pv;
        sacc += pv;
      }
#pragma unroll
      for (int c = 0; c < 2; ++c) {
        unsigned wA0 = pk2(p[8 * c + 0], p[8 * c + 1]);
        unsigned wB0 = pk2(p[8 * c + 2], p[8 * c + 3]);
        unsigned wA1 = pk2(p[8 * c + 4], p[8 * c + 5]);
        unsigned wB1 = pk2(p[8 * c + 6], p[8 * c + 7]);
        pswap(wA0, wA1);  // -> words 0 and 2 of B-frag
        pswap(wB0, wB1);  // -> words 1 and 3
        u32x4 pw;
        pw[0] = wA0; pw[1] = wB0; pw[2] = wA1; pw[3] = wB1;
        bf16x8 pb = __builtin_bit_cast(bf16x8, pw);
        int kc = 2 * t + c;
        // O^T = V^T · P^T : A = V^T (row = d = l31 / l31+32), contiguous keys
        const bf16_t* vrow = Vbase + (size_t)l31 * NN + key0 + kc * 16 + 8 * lh;
        o0 = __builtin_amdgcn_mfma_f32_32x32x16_bf16(ldg8(vrow), pb, o0, 0, 0, 0);
        o1 = __builtin_amdgcn_mfma_f32_32x32x16_bf16(ldg8(vrow + 32 * NN), pb, o1, 0, 0, 0);
      }
    }
  }

  // ---- row sums: combine lane halves, then cross-wave via LDS
  float stot = sacc + __shfl_xor(sacc, 32);
  if (l < 32) Ssum[w][l31] = stot;

  // O^T regs -> LDS: o0[r] is (d = (r&3)+8(r>>2)+4lh, q = l31)
#pragma unroll
  for (int r = 0; r < 16; ++r) {
    int d = (r & 3) + 8 * (r >> 2) + 4 * lh;
    Opart[w][d][l31] = o0[r];
    Opart[w][32 + d][l31] = o1[r];
  }
  __syncthreads();

  // combine 4 wave-partials, normalize, write out
#pragma unroll
  for (int k = 0; k < 8; ++k) {
    int idx = k * 256 + tid;
    int q = idx & 31, d = idx >> 5;
    float s = Ssum[0][q] + Ssum[1][q] + Ssum[2][q] + Ssum[3][q];
    float ov = Opart[0][d][q] + Opart[1][d][q] + Opart[2][d][q] + Opart[3][d][q];
    out[(size_t)(hh * NN + q0 + q) * DOUT + d] = ov / s;
  }
}

extern "C" void kernel_launch(void* const* d_in, const int* in_sizes, int n_in,
                              void* d_out, int out_size, void* d_ws, size_t ws_size,
                              hipStream_t stream) {
  const float* adj = (const float*)d_in[0];
  const float* h   = (const float*)d_in[1];
  const float* WQ  = (const float*)d_in[2];
  const float* bQ  = (const float*)d_in[3];
  const float* WK  = (const float*)d_in[4];
  const float* bK  = (const float*)d_in[5];
  const float* WV  = (const float*)d_in[6];
  const float* bV  = (const float*)d_in[7];
  float* out = (float*)d_out;

  if (ws_size < 12976128) return;  // need ~12.4 MB scratch

  char* ws = (char*)d_ws;
  bf16_t* hb = (bf16_t*)ws;                 // [N][256] bf16            3,145,728 B
  bf16_t* Wt = (bf16_t*)(ws + 3145728);     // [3][H][64][256] bf16       393,216 B
  bf16_t* Qb = (bf16_t*)(ws + 3538944);     // [H][N][64] bf16 (scaled) 3,145,728 B
  bf16_t* Kb = (bf16_t*)(ws + 6684672);     // [H][N][64] bf16          3,145,728 B
  bf16_t* Vt = (bf16_t*)(ws + 9830400);     // [H][64][N] bf16          3,145,728 B

  prep_kernel<<<1024, 256, 0, stream>>>(h, WQ, WK, WV, hb, Wt);
  proj_kernel<<<dim3(96, 4), 256, 0, stream>>>(hb, Wt, bQ, bK, bV, Qb, Kb, Vt);
  attn_kernel<<<dim3(192, 4), 256, 0, stream>>>(adj, Qb, Kb, Vt, out);
}

// Round 3
// 301.115 us; speedup vs baseline: 1.0433x; 1.0433x over previous
//
#include <hip/hip_runtime.h>
#include <hip/hip_bf16.h>

#define NN 6144
#define HEADS 4
#define DIN 256
#define DOUT 64

typedef __bf16 bf16_t;
typedef bf16_t bf16x8 __attribute__((ext_vector_type(8)));
typedef float f32x16 __attribute__((ext_vector_type(16)));
typedef float f32x4 __attribute__((ext_vector_type(4)));
typedef unsigned u32x4 __attribute__((ext_vector_type(4)));

#if __has_builtin(__builtin_amdgcn_exp2f)
#define EXP2(x) __builtin_amdgcn_exp2f(x)
#else
#define EXP2(x) exp2f(x)
#endif

static __device__ __forceinline__ f32x16 zero16() {
  f32x16 z;
#pragma unroll
  for (int i = 0; i < 16; ++i) z[i] = 0.0f;
  return z;
}

static __device__ __forceinline__ bf16x8 ldg8(const bf16_t* p) {
  return *reinterpret_cast<const bf16x8*>(p);
}

// pack two f32 -> one u32 of 2 bf16 (element 0 in low half)
static __device__ __forceinline__ unsigned pk2(float a, float b) {
  union { bf16_t h[2]; unsigned u; } z;
  z.h[0] = (bf16_t)a;
  z.h[1] = (bf16_t)b;
  return z.u;
}

// v_permlane32_swap_b32: x.hi32lanes <-> y.lo32lanes
static __device__ __forceinline__ void pswap(unsigned& x, unsigned& y) {
  asm("v_permlane32_swap_b32 %0, %1" : "+v"(x), "+v"(y));
}

// ---------------- prep: h -> bf16, W -> transposed bf16 (scale folded into WQ)
__global__ __launch_bounds__(256) void prep_kernel(
    const float* __restrict__ h, const float* __restrict__ WQ,
    const float* __restrict__ WK, const float* __restrict__ WV,
    bf16_t* __restrict__ hb, bf16_t* __restrict__ Wt) {
  int stride = gridDim.x * blockDim.x;
  int idx = blockIdx.x * blockDim.x + threadIdx.x;
  for (int i = idx; i < NN * DIN; i += stride)
    hb[i] = (bf16_t)h[i];
  const float c2 = 0.0625f * 1.4426950408889634f;  // (1/sqrt(256)) * log2(e)
  for (int i = idx; i < 3 * HEADS * DOUT * DIN; i += stride) {
    int d = i & (DIN - 1);
    int o = (i >> 8) & (DOUT - 1);
    int hh = (i >> 14) & (HEADS - 1);
    int m = i >> 16;
    const float* W = (m == 0) ? WQ : (m == 1) ? WK : WV;
    float v = W[(hh * DIN + d) * DOUT + o];
    if (m == 0) v *= c2;
    Wt[i] = (bf16_t)v;  // Wt[m][hh][o][d]
  }
}

// ---------------- proj: Qb,Kb row-major bf16 [H][N][64]; Vt bf16 [H][64][N]
__global__ __launch_bounds__(256) void proj_kernel(
    const bf16_t* __restrict__ hb, const bf16_t* __restrict__ Wt,
    const float* __restrict__ bQ, const float* __restrict__ bK,
    const float* __restrict__ bV,
    bf16_t* __restrict__ Qb, bf16_t* __restrict__ Kb, bf16_t* __restrict__ Vt) {
  const float c2 = 0.0625f * 1.4426950408889634f;
  int tid = threadIdx.x;
  int w = tid >> 6, l = tid & 63;
  int l31 = l & 31, lh = l >> 5;
  int hh = blockIdx.y;
  int n0 = blockIdx.x * 64;

#pragma unroll
  for (int s = 0; s < 3; ++s) {
    int t = w * 3 + s;  // 12 tiles: 0-3 Q, 4-7 K, 8-11 V^T
    if (t < 8) {
      int m = t >> 2;            // 0=Q, 1=K
      int rh = (t >> 1) & 1;     // row half
      int oh = t & 1;            // out-col half
      const bf16_t* arow = hb + (n0 + rh * 32 + l31) * DIN + 8 * lh;
      const bf16_t* brow = Wt + ((m * HEADS + hh) * DOUT + oh * 32 + l31) * DIN + 8 * lh;
      f32x16 acc = zero16();
#pragma unroll
      for (int kc = 0; kc < 16; ++kc)
        acc = __builtin_amdgcn_mfma_f32_32x32x16_bf16(ldg8(arow + kc * 16),
                                                      ldg8(brow + kc * 16), acc, 0, 0, 0);
      const float* bias = (m == 0) ? bQ : bK;
      float bv = bias[hh * DOUT + oh * 32 + l31];
      if (m == 0) bv *= c2;
      bf16_t* outp = ((m == 0) ? Qb : Kb) +
                     (size_t)(hh * NN + n0 + rh * 32) * DOUT + oh * 32 + l31;
#pragma unroll
      for (int r = 0; r < 16; ++r) {
        int q = (r & 3) + 8 * (r >> 2) + 4 * lh;
        outp[q * DOUT] = (bf16_t)(acc[r] + bv);
      }
    } else {
      int tt = t - 8;
      int oh = tt >> 1, nh = tt & 1;
      const bf16_t* arow = Wt + ((2 * HEADS + hh) * DOUT + oh * 32 + l31) * DIN + 8 * lh;
      const bf16_t* brow = hb + (n0 + nh * 32 + l31) * DIN + 8 * lh;
      f32x16 acc = zero16();
#pragma unroll
      for (int kc = 0; kc < 16; ++kc)
        acc = __builtin_amdgcn_mfma_f32_32x32x16_bf16(ldg8(arow + kc * 16),
                                                      ldg8(brow + kc * 16), acc, 0, 0, 0);
      bf16_t* outp = Vt + (size_t)(hh * DOUT + oh * 32) * NN + n0 + nh * 32 + l31;
#pragma unroll
      for (int r = 0; r < 16; ++r) {
        int o = (r & 3) + 8 * (r >> 2) + 4 * lh;
        float bvv = bV[hh * DOUT + oh * 32 + o];
        outp[o * NN] = (bf16_t)(acc[r] + bvv);
      }
    }
  }
}

// one pipelined iteration: consume AVC (adj regs loaded last iter), prefetch AVN.
// VMEM issue order matters (FIFO vmcnt): kf (L2) -> vf (L2) -> adj_next (HBM last,
// so K/V waits never drain the HBM prefetch).
#define ATTN_ITER(AVC, AVN, IT)                                                 \
  {                                                                             \
    const int key0 = ((IT) * 4 + w) * 64;                                       \
    const int itn = ((IT) + 1 < 24) ? (IT) + 1 : (IT);                          \
    const float* apn = arow + (itn * 4 + w) * 64;                               \
    const bf16_t* krow = Kbase + (size_t)(key0 + l31) * DOUT + 8 * lh;          \
    const bf16_t* vrow = Vbase + (size_t)l31 * NN + key0 + 8 * lh;              \
    bf16x8 kf[8], vf[8];                                                        \
    _Pragma("unroll") for (int kc = 0; kc < 4; ++kc) {                          \
      kf[kc] = ldg8(krow + kc * 16);                                            \
      kf[4 + kc] = ldg8(krow + 32 * DOUT + kc * 16);                            \
    }                                                                           \
    _Pragma("unroll") for (int kc = 0; kc < 4; ++kc) {                          \
      vf[kc] = ldg8(vrow + kc * 16);                                            \
      vf[4 + kc] = ldg8(vrow + 32 * NN + kc * 16);                              \
    }                                                                           \
    _Pragma("unroll") for (int g = 0; g < 4; ++g) {                             \
      AVN[g] = *reinterpret_cast<const f32x4*>(apn + 8 * g);                    \
      AVN[4 + g] = *reinterpret_cast<const f32x4*>(apn + 32 + 8 * g);           \
    }                                                                           \
    f32x16 s0 = zero16(), s1 = zero16();                                        \
    _Pragma("unroll") for (int kc = 0; kc < 4; ++kc) {                          \
      s0 = __builtin_amdgcn_mfma_f32_32x32x16_bf16(kf[kc], qf[kc], s0, 0, 0, 0);\
      s1 = __builtin_amdgcn_mfma_f32_32x32x16_bf16(kf[4 + kc], qf[kc], s1, 0, 0, 0);\
    }                                                                           \
    _Pragma("unroll") for (int t = 0; t < 2; ++t) {                             \
      f32x16 st = t ? s1 : s0;                                                  \
      float p[16];                                                              \
      _Pragma("unroll") for (int r = 0; r < 16; ++r) {                          \
        float pv = EXP2(st[r] * AVC[4 * t + (r >> 2)][r & 3]);                  \
        p[r] = pv;                                                              \
        sacc += pv;                                                             \
      }                                                                         \
      _Pragma("unroll") for (int c = 0; c < 2; ++c) {                           \
        unsigned wA0 = pk2(p[8 * c + 0], p[8 * c + 1]);                         \
        unsigned wB0 = pk2(p[8 * c + 2], p[8 * c + 3]);                         \
        unsigned wA1 = pk2(p[8 * c + 4], p[8 * c + 5]);                         \
        unsigned wB1 = pk2(p[8 * c + 6], p[8 * c + 7]);                         \
        pswap(wA0, wA1);                                                        \
        pswap(wB0, wB1);                                                        \
        u32x4 pw;                                                               \
        pw[0] = wA0; pw[1] = wB0; pw[2] = wA1; pw[3] = wB1;                     \
        bf16x8 pb = __builtin_bit_cast(bf16x8, pw);                             \
        const int kc = 2 * t + c;                                               \
        o0 = __builtin_amdgcn_mfma_f32_32x32x16_bf16(vf[kc], pb, o0, 0, 0, 0);  \
        o1 = __builtin_amdgcn_mfma_f32_32x32x16_bf16(vf[4 + kc], pb, o1, 0, 0, 0);\
      }                                                                         \
    }                                                                           \
  }

// ---------------- attention: swapped QK^T, in-reg softmax, depth-1 VMEM pipeline
__global__ __launch_bounds__(256, 2) void attn_kernel(
    const float* __restrict__ adj, const bf16_t* __restrict__ Qb,
    const bf16_t* __restrict__ Kb, const bf16_t* __restrict__ Vt,
    float* __restrict__ out) {
  __shared__ float Opart[4][64][32];  // [wave][d][q]
  __shared__ float Ssum[4][32];

  int tid = threadIdx.x;
  int w = tid >> 6, l = tid & 63;
  int l31 = l & 31, lh = l >> 5;
  int hh = blockIdx.y;
  int q0 = blockIdx.x * 32;

  // Q as B-fragment: col = q = l31, k = kc*16 + 8*lh + 0..7  (pre-scaled by c2)
  const bf16_t* Qrow = Qb + (size_t)(hh * NN + q0 + l31) * DOUT + 8 * lh;
  bf16x8 qf[4];
#pragma unroll
  for (int kc = 0; kc < 4; ++kc) qf[kc] = ldg8(Qrow + kc * 16);

  const bf16_t* Kbase = Kb + (size_t)hh * NN * DOUT;
  const bf16_t* Vbase = Vt + (size_t)hh * DOUT * NN;
  // this thread streams adj row q = q0 + l31; lh selects 16B sub-chunk
  const float* arow = adj + (size_t)hh * NN * NN + (size_t)(q0 + l31) * NN + 4 * lh;

  f32x16 o0 = zero16(), o1 = zero16();
  float sacc = 0.0f;

  // prologue: prefetch adj for it=0
  f32x4 avA[8], avB[8];
  {
    const float* ap0 = arow + (0 * 4 + w) * 64;
#pragma unroll
    for (int g = 0; g < 4; ++g) {
      avA[g] = *reinterpret_cast<const f32x4*>(ap0 + 8 * g);
      avA[4 + g] = *reinterpret_cast<const f32x4*>(ap0 + 32 + 8 * g);
    }
  }

  for (int it2 = 0; it2 < 12; ++it2) {
    ATTN_ITER(avA, avB, 2 * it2);
    ATTN_ITER(avB, avA, 2 * it2 + 1);
  }

  // ---- row sums: combine lane halves, then cross-wave via LDS
  float stot = sacc + __shfl_xor(sacc, 32);
  if (l < 32) Ssum[w][l31] = stot;

  // O^T regs -> LDS: o0[r] is (d = (r&3)+8(r>>2)+4lh, q = l31)
#pragma unroll
  for (int r = 0; r < 16; ++r) {
    int d = (r & 3) + 8 * (r >> 2) + 4 * lh;
    Opart[w][d][l31] = o0[r];
    Opart[w][32 + d][l31] = o1[r];
  }
  __syncthreads();

  // combine 4 wave-partials, normalize, write out
#pragma unroll
  for (int k = 0; k < 8; ++k) {
    int idx = k * 256 + tid;
    int q = idx & 31, d = idx >> 5;
    float s = Ssum[0][q] + Ssum[1][q] + Ssum[2][q] + Ssum[3][q];
    float ov = Opart[0][d][q] + Opart[1][d][q] + Opart[2][d][q] + Opart[3][d][q];
    out[(size_t)(hh * NN + q0 + q) * DOUT + d] = ov / s;
  }
}

extern "C" void kernel_launch(void* const* d_in, const int* in_sizes, int n_in,
                              void* d_out, int out_size, void* d_ws, size_t ws_size,
                              hipStream_t stream) {
  const float* adj = (const float*)d_in[0];
  const float* h   = (const float*)d_in[1];
  const float* WQ  = (const float*)d_in[2];
  const float* bQ  = (const float*)d_in[3];
  const float* WK  = (const float*)d_in[4];
  const float* bK  = (const float*)d_in[5];
  const float* WV  = (const float*)d_in[6];
  const float* bV  = (const float*)d_in[7];
  float* out = (float*)d_out;

  if (ws_size < 12976128) return;  // need ~12.4 MB scratch

  char* ws = (char*)d_ws;
  bf16_t* hb = (bf16_t*)ws;                 // [N][256] bf16            3,145,728 B
  bf16_t* Wt = (bf16_t*)(ws + 3145728);     // [3][H][64][256] bf16       393,216 B
  bf16_t* Qb = (bf16_t*)(ws + 3538944);     // [H][N][64] bf16 (scaled) 3,145,728 B
  bf16_t* Kb = (bf16_t*)(ws + 6684672);     // [H][N][64] bf16          3,145,728 B
  bf16_t* Vt = (bf16_t*)(ws + 9830400);     // [H][64][N] bf16          3,145,728 B

  prep_kernel<<<1024, 256, 0, stream>>>(h, WQ, WK, WV, hb, Wt);
  proj_kernel<<<dim3(96, 4), 256, 0, stream>>>(hb, Wt, bQ, bK, bV, Qb, Kb, Vt);
  attn_kernel<<<dim3(192, 4), 256, 0, stream>>>(adj, Qb, Kb, Vt, out);
}

// Round 4
// 192.125 us; speedup vs baseline: 1.6351x; 1.5673x over previous
//
#include <hip/hip_runtime.h>
#include <hip/hip_bf16.h>

#define NN 6144
#define HEADS 4
#define DIN 256
#define DOUT 64

typedef __bf16 bf16_t;
typedef bf16_t bf16x8 __attribute__((ext_vector_type(8)));
typedef float f32x16 __attribute__((ext_vector_type(16)));
typedef float f32x4 __attribute__((ext_vector_type(4)));
typedef unsigned u32x4 __attribute__((ext_vector_type(4)));

#if __has_builtin(__builtin_amdgcn_exp2f)
#define EXP2(x) __builtin_amdgcn_exp2f(x)
#else
#define EXP2(x) exp2f(x)
#endif

static __device__ __forceinline__ f32x16 zero16() {
  f32x16 z;
#pragma unroll
  for (int i = 0; i < 16; ++i) z[i] = 0.0f;
  return z;
}

static __device__ __forceinline__ bf16x8 ldg8(const bf16_t* p) {
  return *reinterpret_cast<const bf16x8*>(p);
}

// pack two f32 -> one u32 of 2 bf16 (element 0 in low half)
static __device__ __forceinline__ unsigned pk2(float a, float b) {
  union { bf16_t h[2]; unsigned u; } z;
  z.h[0] = (bf16_t)a;
  z.h[1] = (bf16_t)b;
  return z.u;
}

// v_permlane32_swap_b32: x.hi32lanes <-> y.lo32lanes
static __device__ __forceinline__ void pswap(unsigned& x, unsigned& y) {
  asm("v_permlane32_swap_b32 %0, %1" : "+v"(x), "+v"(y));
}

// async global->LDS, 16B per lane. LDS dest = wave-uniform base + lane*16.
// as3 pointer obtained by low-32 truncation of the generic LDS address
// (AMDGPU flat->local cast is exactly that); as1 is value-identical.
static __device__ __forceinline__ void gload_lds16(const float* g, float* lds) {
  __builtin_amdgcn_global_load_lds(
      (const __attribute__((address_space(1))) unsigned*)(uintptr_t)g,
      (__attribute__((address_space(3))) unsigned*)(unsigned)(uintptr_t)lds,
      16, 0, 0);
}

// ---------------- prep: h -> bf16, W -> transposed bf16 (scale folded into WQ)
__global__ __launch_bounds__(256) void prep_kernel(
    const float* __restrict__ h, const float* __restrict__ WQ,
    const float* __restrict__ WK, const float* __restrict__ WV,
    bf16_t* __restrict__ hb, bf16_t* __restrict__ Wt) {
  int stride = gridDim.x * blockDim.x;
  int idx = blockIdx.x * blockDim.x + threadIdx.x;
  for (int i = idx; i < NN * DIN; i += stride)
    hb[i] = (bf16_t)h[i];
  const float c2 = 0.0625f * 1.4426950408889634f;  // (1/sqrt(256)) * log2(e)
  for (int i = idx; i < 3 * HEADS * DOUT * DIN; i += stride) {
    int d = i & (DIN - 1);
    int o = (i >> 8) & (DOUT - 1);
    int hh = (i >> 14) & (HEADS - 1);
    int m = i >> 16;
    const float* W = (m == 0) ? WQ : (m == 1) ? WK : WV;
    float v = W[(hh * DIN + d) * DOUT + o];
    if (m == 0) v *= c2;
    Wt[i] = (bf16_t)v;  // Wt[m][hh][o][d]
  }
}

// ---------------- proj: Qb row-major [H][N][64]; Kf/Vf in MFMA-fragment order.
// Kf elem addr: h*393216 + (key>>6)*4096 + ((key>>5)&1)*2048 + (o>>4)*512
//               + ((o>>3)&1)*256 + (key&31)*8 + (o&7)
// Vf elem addr: h*393216 + (key>>6)*4096 + (d>>5)*2048 + ((key>>4)&3)*512
//               + ((key>>3)&1)*256 + (d&31)*8 + (key&7)
__global__ __launch_bounds__(256) void proj_kernel(
    const bf16_t* __restrict__ hb, const bf16_t* __restrict__ Wt,
    const float* __restrict__ bQ, const float* __restrict__ bK,
    const float* __restrict__ bV,
    bf16_t* __restrict__ Qb, bf16_t* __restrict__ Kf, bf16_t* __restrict__ Vf) {
  const float c2 = 0.0625f * 1.4426950408889634f;
  int tid = threadIdx.x;
  int w = tid >> 6, l = tid & 63;
  int l31 = l & 31, lh = l >> 5;
  int hh = blockIdx.y;
  int n0 = blockIdx.x * 64;

#pragma unroll
  for (int s = 0; s < 3; ++s) {
    int t = w * 3 + s;  // 12 tiles: 0-3 Q, 4-7 K, 8-11 V^T
    if (t < 8) {
      int m = t >> 2;            // 0=Q, 1=K
      int rh = (t >> 1) & 1;     // row half (key half)
      int oh = t & 1;            // out-col half
      const bf16_t* arow = hb + (n0 + rh * 32 + l31) * DIN + 8 * lh;
      const bf16_t* brow = Wt + ((m * HEADS + hh) * DOUT + oh * 32 + l31) * DIN + 8 * lh;
      f32x16 acc = zero16();
#pragma unroll
      for (int kc = 0; kc < 16; ++kc)
        acc = __builtin_amdgcn_mfma_f32_32x32x16_bf16(ldg8(arow + kc * 16),
                                                      ldg8(brow + kc * 16), acc, 0, 0, 0);
      const float* bias = (m == 0) ? bQ : bK;
      float bv = bias[hh * DOUT + oh * 32 + l31];
      if (m == 0) {
        bv *= c2;
        bf16_t* outp = Qb + (size_t)(hh * NN + n0 + rh * 32) * DOUT + oh * 32 + l31;
#pragma unroll
        for (int r = 0; r < 16; ++r) {
          int q = (r & 3) + 8 * (r >> 2) + 4 * lh;
          outp[q * DOUT] = (bf16_t)(acc[r] + bv);
        }
      } else {
        // K fragment write: o = oh*32 + l31 (fixed per thread), key = n0 + rh*32 + rr
        int o = oh * 32 + l31;
        bf16_t* outp = Kf + (size_t)hh * 393216 + (n0 >> 6) * 4096 + rh * 2048 +
                       (o >> 4) * 512 + ((o >> 3) & 1) * 256 + (o & 7);
#pragma unroll
        for (int r = 0; r < 16; ++r) {
          int rr = (r & 3) + 8 * (r >> 2) + 4 * lh;  // key & 31
          outp[rr * 8] = (bf16_t)(acc[r] + bv);
        }
      }
    } else {
      int tt = t - 8;
      int oh = tt >> 1, nh = tt & 1;  // oh = d half, nh = key half
      const bf16_t* arow = Wt + ((2 * HEADS + hh) * DOUT + oh * 32 + l31) * DIN + 8 * lh;
      const bf16_t* brow = hb + (n0 + nh * 32 + l31) * DIN + 8 * lh;
      f32x16 acc = zero16();
#pragma unroll
      for (int kc = 0; kc < 16; ++kc)
        acc = __builtin_amdgcn_mfma_f32_32x32x16_bf16(ldg8(arow + kc * 16),
                                                      ldg8(brow + kc * 16), acc, 0, 0, 0);
      // V fragment write: key = n0 + nh*32 + l31 (fixed), d = oh*32 + rr
      int keyloc = nh * 32 + l31;
      bf16_t* outp = Vf + (size_t)hh * 393216 + (n0 >> 6) * 4096 + oh * 2048 +
                     (keyloc >> 4) * 512 + ((keyloc >> 3) & 1) * 256 + (keyloc & 7);
#pragma unroll
      for (int r = 0; r < 16; ++r) {
        int rr = (r & 3) + 8 * (r >> 2) + 4 * lh;  // d & 31
        float bvv = bV[hh * DOUT + oh * 32 + rr];
        outp[rr * 8] = (bf16_t)(acc[r] + bvv);
      }
    }
  }
}

// ---------------- attention: adj via swizzled global_load_lds double-buffer;
// K/V via contiguous fragment loads; swapped QK^T; in-register softmax.
__global__ __launch_bounds__(256, 2) void attn_kernel(
    const float* __restrict__ adj, const bf16_t* __restrict__ Qb,
    const bf16_t* __restrict__ Kf, const bf16_t* __restrict__ Vf,
    float* __restrict__ out) {
  __shared__ __align__(16) float smem[2][32][256];  // 64 KB; reused for epilogue

  int tid = threadIdx.x;
  int w = tid >> 6, l = tid & 63;
  int l31 = l & 31, lh = l >> 5;
  int hh = blockIdx.y;
  int q0 = blockIdx.x * 32;

  // Q as B-fragment: col = q = l31, k = kc*16 + 8*lh + 0..7  (pre-scaled by c2)
  const bf16_t* Qrow = Qb + (size_t)(hh * NN + q0 + l31) * DOUT + 8 * lh;
  bf16x8 qf[4];
#pragma unroll
  for (int kc = 0; kc < 4; ++kc) qf[kc] = ldg8(Qrow + kc * 16);

  const bf16_t* Kh = Kf + (size_t)hh * 393216;
  const bf16_t* Vh = Vf + (size_t)hh * 393216;
  const float* adjq = adj + (size_t)hh * NN * NN + (size_t)q0 * NN;

  f32x16 o0 = zero16(), o1 = zero16();
  float sacc = 0.0f;

  // prologue: stage adj tile 0 into buf 0 (wave w stages rows 8w..8w+7;
  // source chunk pre-swizzled so the LDS readback swizzle is consistent)
#pragma unroll
  for (int i = 0; i < 8; ++i) {
    int row = 8 * w + i;
    gload_lds16(adjq + (size_t)row * NN + ((l ^ i) << 2), &smem[0][row][0]);
  }
  __syncthreads();

  for (int it = 0; it < 24; ++it) {
    int cur = it & 1;
    int chunk = it * 4 + w;  // this wave's 64-key chunk

    // K/V fragments: contiguous 1KB wave loads (issued first; their waits
    // never drain the adj stage, which is issued after)
    const bf16_t* kbase = Kh + (size_t)chunk * 4096 + l * 8;
    const bf16_t* vbase = Vh + (size_t)chunk * 4096 + l * 8;
    bf16x8 kf[8], vf[8];
#pragma unroll
    for (int x = 0; x < 4; ++x) {
      kf[x] = ldg8(kbase + x * 512);
      kf[4 + x] = ldg8(kbase + 2048 + x * 512);
    }
#pragma unroll
    for (int x = 0; x < 4; ++x) {
      vf[x] = ldg8(vbase + x * 512);
      vf[4 + x] = ldg8(vbase + 2048 + x * 512);
    }

    // stage next adj tile into the other buffer
    if (it + 1 < 24) {
#pragma unroll
      for (int i = 0; i < 8; ++i) {
        int row = 8 * w + i;
        gload_lds16(adjq + (size_t)row * NN + (it + 1) * 256 + ((l ^ i) << 2),
                    &smem[cur ^ 1][row][0]);
      }
    }

    // adj readback: row = own q (l31), swizzled chunk
    f32x4 av[8];
#pragma unroll
    for (int t2 = 0; t2 < 2; ++t2)
#pragma unroll
      for (int g = 0; g < 4; ++g) {
        int c = 16 * w + 8 * t2 + 2 * g + lh;
        av[t2 * 4 + g] =
            *reinterpret_cast<const f32x4*>(&smem[cur][l31][(c ^ (l31 & 7)) << 2]);
      }

    // S^T = K · Q^T : row = key (reg), col = q (lane)
    f32x16 s0 = zero16(), s1 = zero16();
#pragma unroll
    for (int kc = 0; kc < 4; ++kc) {
      s0 = __builtin_amdgcn_mfma_f32_32x32x16_bf16(kf[kc], qf[kc], s0, 0, 0, 0);
      s1 = __builtin_amdgcn_mfma_f32_32x32x16_bf16(kf[4 + kc], qf[kc], s1, 0, 0, 0);
    }

    // P = exp2(S^T * adj); pack + permlane32_swap into PV B-frags; PV MFMA
#pragma unroll
    for (int t2 = 0; t2 < 2; ++t2) {
      f32x16 st = t2 ? s1 : s0;
      float p[16];
#pragma unroll
      for (int r = 0; r < 16; ++r) {
        float pv = EXP2(st[r] * av[4 * t2 + (r >> 2)][r & 3]);
        p[r] = pv;
        sacc += pv;
      }
#pragma unroll
      for (int c = 0; c < 2; ++c) {
        unsigned wA0 = pk2(p[8 * c + 0], p[8 * c + 1]);
        unsigned wB0 = pk2(p[8 * c + 2], p[8 * c + 3]);
        unsigned wA1 = pk2(p[8 * c + 4], p[8 * c + 5]);
        unsigned wB1 = pk2(p[8 * c + 6], p[8 * c + 7]);
        pswap(wA0, wA1);
        pswap(wB0, wB1);
        u32x4 pw;
        pw[0] = wA0; pw[1] = wB0; pw[2] = wA1; pw[3] = wB1;
        bf16x8 pb = __builtin_bit_cast(bf16x8, pw);
        int kc = 2 * t2 + c;
        o0 = __builtin_amdgcn_mfma_f32_32x32x16_bf16(vf[kc], pb, o0, 0, 0, 0);
        o1 = __builtin_amdgcn_mfma_f32_32x32x16_bf16(vf[4 + kc], pb, o1, 0, 0, 0);
      }
    }

    __syncthreads();  // buf[cur] reads done; stage of buf[cur^1] drained
  }

  // ---- epilogue: reuse smem for cross-wave combine
  float stot = sacc + __shfl_xor(sacc, 32);
  float* opart = &smem[0][0][0];        // [4][64][32]
  float* ssum = &smem[0][0][0] + 8192;  // [4][32]
  if (l < 32) ssum[w * 32 + l31] = stot;
#pragma unroll
  for (int r = 0; r < 16; ++r) {
    int d = (r & 3) + 8 * (r >> 2) + 4 * lh;
    opart[w * 2048 + d * 32 + l31] = o0[r];
    opart[w * 2048 + (32 + d) * 32 + l31] = o1[r];
  }
  __syncthreads();

#pragma unroll
  for (int k = 0; k < 8; ++k) {
    int idx = k * 256 + tid;
    int q = idx & 31, d = idx >> 5;
    float s = ssum[q] + ssum[32 + q] + ssum[64 + q] + ssum[96 + q];
    float ov = opart[d * 32 + q] + opart[2048 + d * 32 + q] +
               opart[4096 + d * 32 + q] + opart[6144 + d * 32 + q];
    out[(size_t)(hh * NN + q0 + q) * DOUT + d] = ov / s;
  }
}

extern "C" void kernel_launch(void* const* d_in, const int* in_sizes, int n_in,
                              void* d_out, int out_size, void* d_ws, size_t ws_size,
                              hipStream_t stream) {
  const float* adj = (const float*)d_in[0];
  const float* h   = (const float*)d_in[1];
  const float* WQ  = (const float*)d_in[2];
  const float* bQ  = (const float*)d_in[3];
  const float* WK  = (const float*)d_in[4];
  const float* bK  = (const float*)d_in[5];
  const float* WV  = (const float*)d_in[6];
  const float* bV  = (const float*)d_in[7];
  float* out = (float*)d_out;

  if (ws_size < 12976128) return;  // need ~12.4 MB scratch

  char* ws = (char*)d_ws;
  bf16_t* hb = (bf16_t*)ws;                 // [N][256] bf16            3,145,728 B
  bf16_t* Wt = (bf16_t*)(ws + 3145728);     // [3][H][64][256] bf16       393,216 B
  bf16_t* Qb = (bf16_t*)(ws + 3538944);     // [H][N][64] bf16 (scaled) 3,145,728 B
  bf16_t* Kf = (bf16_t*)(ws + 6684672);     // [H] K fragments          3,145,728 B
  bf16_t* Vf = (bf16_t*)(ws + 9830400);     // [H] V fragments          3,145,728 B

  prep_kernel<<<1024, 256, 0, stream>>>(h, WQ, WK, WV, hb, Wt);
  proj_kernel<<<dim3(96, 4), 256, 0, stream>>>(hb, Wt, bQ, bK, bV, Qb, Kf, Vf);
  attn_kernel<<<dim3(192, 4), 256, 0, stream>>>(adj, Qb, Kf, Vf, out);
}

// Round 6
// 188.006 us; speedup vs baseline: 1.6710x; 1.0219x over previous
//
#include <hip/hip_runtime.h>
#include <hip/hip_bf16.h>

#define NN 6144
#define HEADS 4
#define DIN 256
#define DOUT 64

typedef __bf16 bf16_t;
typedef bf16_t bf16x8 __attribute__((ext_vector_type(8)));
typedef float f32x16 __attribute__((ext_vector_type(16)));
typedef float f32x4 __attribute__((ext_vector_type(4)));
typedef unsigned u32x4 __attribute__((ext_vector_type(4)));

#if __has_builtin(__builtin_amdgcn_exp2f)
#define EXP2(x) __builtin_amdgcn_exp2f(x)
#else
#define EXP2(x) exp2f(x)
#endif

static __device__ __forceinline__ f32x16 zero16() {
  f32x16 z;
#pragma unroll
  for (int i = 0; i < 16; ++i) z[i] = 0.0f;
  return z;
}

static __device__ __forceinline__ bf16x8 ldg8(const bf16_t* p) {
  return *reinterpret_cast<const bf16x8*>(p);
}

// pack two f32 -> one u32 of 2 bf16 (element 0 in low half)
static __device__ __forceinline__ unsigned pk2(float a, float b) {
  union { bf16_t h[2]; unsigned u; } z;
  z.h[0] = (bf16_t)a;
  z.h[1] = (bf16_t)b;
  return z.u;
}

// v_permlane32_swap_b32: x.hi32lanes <-> y.lo32lanes
static __device__ __forceinline__ void pswap(unsigned& x, unsigned& y) {
  asm("v_permlane32_swap_b32 %0, %1" : "+v"(x), "+v"(y));
}

// async global->LDS, 16B per lane. LDS dest = wave-uniform base + lane*16.
static __device__ __forceinline__ void gload_lds16(const float* g, float* lds) {
  __builtin_amdgcn_global_load_lds(
      (const __attribute__((address_space(1))) unsigned*)(uintptr_t)g,
      (__attribute__((address_space(3))) unsigned*)(unsigned)(uintptr_t)lds,
      16, 0, 0);
}

// ---------------- prep: h -> bf16, W -> transposed bf16 (scale folded into WQ)
__global__ __launch_bounds__(256) void prep_kernel(
    const float* __restrict__ h, const float* __restrict__ WQ,
    const float* __restrict__ WK, const float* __restrict__ WV,
    bf16_t* __restrict__ hb, bf16_t* __restrict__ Wt) {
  int stride = gridDim.x * blockDim.x;
  int idx = blockIdx.x * blockDim.x + threadIdx.x;
  for (int i = idx; i < NN * DIN; i += stride)
    hb[i] = (bf16_t)h[i];
  const float c2 = 0.0625f * 1.4426950408889634f;  // (1/sqrt(256)) * log2(e)
  for (int i = idx; i < 3 * HEADS * DOUT * DIN; i += stride) {
    int d = i & (DIN - 1);
    int o = (i >> 8) & (DOUT - 1);
    int hh = (i >> 14) & (HEADS - 1);
    int m = i >> 16;
    const float* W = (m == 0) ? WQ : (m == 1) ? WK : WV;
    float v = W[(hh * DIN + d) * DOUT + o];
    if (m == 0) v *= c2;
    Wt[i] = (bf16_t)v;  // Wt[m][hh][o][d]
  }
}

// ---------------- proj: Qb row-major [H][N][64]; Kf/Vf in MFMA-fragment order.
__global__ __launch_bounds__(256) void proj_kernel(
    const bf16_t* __restrict__ hb, const bf16_t* __restrict__ Wt,
    const float* __restrict__ bQ, const float* __restrict__ bK,
    const float* __restrict__ bV,
    bf16_t* __restrict__ Qb, bf16_t* __restrict__ Kf, bf16_t* __restrict__ Vf) {
  const float c2 = 0.0625f * 1.4426950408889634f;
  int tid = threadIdx.x;
  int w = tid >> 6, l = tid & 63;
  int l31 = l & 31, lh = l >> 5;
  int hh = blockIdx.y;
  int n0 = blockIdx.x * 64;

#pragma unroll
  for (int s = 0; s < 3; ++s) {
    int t = w * 3 + s;  // 12 tiles: 0-3 Q, 4-7 K, 8-11 V^T
    if (t < 8) {
      int m = t >> 2;            // 0=Q, 1=K
      int rh = (t >> 1) & 1;     // row half (key half)
      int oh = t & 1;            // out-col half
      const bf16_t* arow = hb + (n0 + rh * 32 + l31) * DIN + 8 * lh;
      const bf16_t* brow = Wt + ((m * HEADS + hh) * DOUT + oh * 32 + l31) * DIN + 8 * lh;
      f32x16 acc = zero16();
#pragma unroll
      for (int kc = 0; kc < 16; ++kc)
        acc = __builtin_amdgcn_mfma_f32_32x32x16_bf16(ldg8(arow + kc * 16),
                                                      ldg8(brow + kc * 16), acc, 0, 0, 0);
      const float* bias = (m == 0) ? bQ : bK;
      float bv = bias[hh * DOUT + oh * 32 + l31];
      if (m == 0) {
        bv *= c2;
        bf16_t* outp = Qb + (size_t)(hh * NN + n0 + rh * 32) * DOUT + oh * 32 + l31;
#pragma unroll
        for (int r = 0; r < 16; ++r) {
          int q = (r & 3) + 8 * (r >> 2) + 4 * lh;
          outp[q * DOUT] = (bf16_t)(acc[r] + bv);
        }
      } else {
        int o = oh * 32 + l31;
        bf16_t* outp = Kf + (size_t)hh * 393216 + (n0 >> 6) * 4096 + rh * 2048 +
                       (o >> 4) * 512 + ((o >> 3) & 1) * 256 + (o & 7);
#pragma unroll
        for (int r = 0; r < 16; ++r) {
          int rr = (r & 3) + 8 * (r >> 2) + 4 * lh;  // key & 31
          outp[rr * 8] = (bf16_t)(acc[r] + bv);
        }
      }
    } else {
      int tt = t - 8;
      int oh = tt >> 1, nh = tt & 1;  // oh = d half, nh = key half
      const bf16_t* arow = Wt + ((2 * HEADS + hh) * DOUT + oh * 32 + l31) * DIN + 8 * lh;
      const bf16_t* brow = hb + (n0 + nh * 32 + l31) * DIN + 8 * lh;
      f32x16 acc = zero16();
#pragma unroll
      for (int kc = 0; kc < 16; ++kc)
        acc = __builtin_amdgcn_mfma_f32_32x32x16_bf16(ldg8(arow + kc * 16),
                                                      ldg8(brow + kc * 16), acc, 0, 0, 0);
      int keyloc = nh * 32 + l31;
      bf16_t* outp = Vf + (size_t)hh * 393216 + (n0 >> 6) * 4096 + oh * 2048 +
                     (keyloc >> 4) * 512 + ((keyloc >> 3) & 1) * 256 + (keyloc & 7);
#pragma unroll
      for (int r = 0; r < 16; ++r) {
        int rr = (r & 3) + 8 * (r >> 2) + 4 * lh;  // d & 31
        float bvv = bV[hh * DOUT + oh * 32 + rr];
        outp[rr * 8] = (bf16_t)(acc[r] + bvv);
      }
    }
  }
}

// ---------------- attention: counted-vmcnt pipeline, WAR-safe stage placement.
// Per iter: K/V issue -> vmcnt(16) [drains only stage(it)] -> s_barrier ->
// stage(it+1) issue [AFTER barrier: nobody still reads buf[cur^1]] ->
// readback/compute. Stage loads stay in flight across the whole compute phase.
__global__ __launch_bounds__(256, 2) void attn_kernel(
    const float* __restrict__ adj, const bf16_t* __restrict__ Qb,
    const bf16_t* __restrict__ Kf, const bf16_t* __restrict__ Vf,
    float* __restrict__ out) {
  __shared__ __align__(16) float smem[2][32][256];  // 64 KB; reused for epilogue

  int tid = threadIdx.x;
  int w = tid >> 6, l = tid & 63;
  int l31 = l & 31, lh = l >> 5;
  int hh = blockIdx.y;
  int q0 = blockIdx.x * 32;

  // Q as B-fragment: col = q = l31, k = kc*16 + 8*lh + 0..7  (pre-scaled by c2)
  const bf16_t* Qrow = Qb + (size_t)(hh * NN + q0 + l31) * DOUT + 8 * lh;
  bf16x8 qf[4];
#pragma unroll
  for (int kc = 0; kc < 4; ++kc) qf[kc] = ldg8(Qrow + kc * 16);

  const bf16_t* Kh = Kf + (size_t)hh * 393216;
  const bf16_t* Vh = Vf + (size_t)hh * 393216;
  const float* adjq = adj + (size_t)hh * NN * NN + (size_t)q0 * NN;

  f32x16 o0 = zero16(), o1 = zero16();
  float sacc = 0.0f;

  // prologue: stage adj tile 0 into buf 0 (wave w stages rows 8w..8w+7;
  // source chunk pre-swizzled so the LDS readback swizzle is consistent)
#pragma unroll
  for (int i = 0; i < 8; ++i) {
    int row = 8 * w + i;
    gload_lds16(adjq + (size_t)row * NN + ((l ^ i) << 2), &smem[0][row][0]);
  }

  for (int it = 0; it < 24; ++it) {
    int cur = it & 1;
    int chunk = it * 4 + w;  // this wave's 64-key chunk

    // ---- K/V fragments first (16 VMEM; stay in flight across the wait below)
    const bf16_t* kbase = Kh + (size_t)chunk * 4096 + l * 8;
    const bf16_t* vbase = Vh + (size_t)chunk * 4096 + l * 8;
    bf16x8 kf[8], vf[8];
#pragma unroll
    for (int x = 0; x < 4; ++x) {
      kf[x] = ldg8(kbase + x * 512);
      kf[4 + x] = ldg8(kbase + 2048 + x * 512);
    }
#pragma unroll
    for (int x = 0; x < 4; ++x) {
      vf[x] = ldg8(vbase + x * 512);
      vf[4 + x] = ldg8(vbase + 2048 + x * 512);
    }
    __builtin_amdgcn_sched_barrier(0);  // all 16 K/V issued before the wait

    // ---- wait for stage(it) (oldest 8 outstanding), keep K/V in flight
    asm volatile("s_waitcnt vmcnt(16)" ::: "memory");
    __builtin_amdgcn_sched_barrier(0);
    __builtin_amdgcn_s_barrier();
    __builtin_amdgcn_sched_barrier(0);

    // ---- stage next adj tile AFTER the barrier (WAR-safe). Dummy re-stage of
    // tile 23 on the last iter keeps counts uniform; drained before epilogue.
    int nt = (it + 1 < 24) ? it + 1 : 23;
#pragma unroll
    for (int i = 0; i < 8; ++i) {
      int row = 8 * w + i;
      gload_lds16(adjq + (size_t)row * NN + nt * 256 + ((l ^ i) << 2),
                  &smem[cur ^ 1][row][0]);
    }
    __builtin_amdgcn_sched_barrier(0);

    // ---- adj readback: row = own q (l31), swizzled chunk
    f32x4 av[8];
#pragma unroll
    for (int t2 = 0; t2 < 2; ++t2)
#pragma unroll
      for (int g = 0; g < 4; ++g) {
        int c = 16 * w + 8 * t2 + 2 * g + lh;
        av[t2 * 4 + g] =
            *reinterpret_cast<const f32x4*>(&smem[cur][l31][(c ^ (l31 & 7)) << 2]);
      }

    // ---- S^T = K · Q^T : row = key (reg), col = q (lane)
    f32x16 s0 = zero16(), s1 = zero16();
#pragma unroll
    for (int kc = 0; kc < 4; ++kc) {
      s0 = __builtin_amdgcn_mfma_f32_32x32x16_bf16(kf[kc], qf[kc], s0, 0, 0, 0);
      s1 = __builtin_amdgcn_mfma_f32_32x32x16_bf16(kf[4 + kc], qf[kc], s1, 0, 0, 0);
    }

    // ---- P = exp2(S^T * adj); pack + permlane32_swap into PV B-frags; PV MFMA
#pragma unroll
    for (int t2 = 0; t2 < 2; ++t2) {
      f32x16 st = t2 ? s1 : s0;
      float p[16];
#pragma unroll
      for (int r = 0; r < 16; ++r) {
        float pv = EXP2(st[r] * av[4 * t2 + (r >> 2)][r & 3]);
        p[r] = pv;
        sacc += pv;
      }
#pragma unroll
      for (int c = 0; c < 2; ++c) {
        unsigned wA0 = pk2(p[8 * c + 0], p[8 * c + 1]);
        unsigned wB0 = pk2(p[8 * c + 2], p[8 * c + 3]);
        unsigned wA1 = pk2(p[8 * c + 4], p[8 * c + 5]);
        unsigned wB1 = pk2(p[8 * c + 6], p[8 * c + 7]);
        pswap(wA0, wA1);
        pswap(wB0, wB1);
        u32x4 pw;
        pw[0] = wA0; pw[1] = wB0; pw[2] = wA1; pw[3] = wB1;
        bf16x8 pb = __builtin_bit_cast(bf16x8, pw);
        int kc = 2 * t2 + c;
        o0 = __builtin_amdgcn_mfma_f32_32x32x16_bf16(vf[kc], pb, o0, 0, 0, 0);
        o1 = __builtin_amdgcn_mfma_f32_32x32x16_bf16(vf[4 + kc], pb, o1, 0, 0, 0);
      }
    }
    // next iteration's vmcnt(16)+s_barrier is the sync point; stage(it+1)
    // writes only buf[cur^1], which nobody reads in this window.
  }

  // drain the dummy stage before smem is reused, then block-wide sync
  asm volatile("s_waitcnt vmcnt(0)" ::: "memory");
  __syncthreads();

  // ---- epilogue: reuse smem for cross-wave combine
  float stot = sacc + __shfl_xor(sacc, 32);
  float* opart = &smem[0][0][0];        // [4][64][32]
  float* ssum = &smem[0][0][0] + 8192;  // [4][32]
  if (l < 32) ssum[w * 32 + l31] = stot;
#pragma unroll
  for (int r = 0; r < 16; ++r) {
    int d = (r & 3) + 8 * (r >> 2) + 4 * lh;
    opart[w * 2048 + d * 32 + l31] = o0[r];
    opart[w * 2048 + (32 + d) * 32 + l31] = o1[r];
  }
  __syncthreads();

#pragma unroll
  for (int k = 0; k < 8; ++k) {
    int idx = k * 256 + tid;
    int q = idx & 31, d = idx >> 5;
    float s = ssum[q] + ssum[32 + q] + ssum[64 + q] + ssum[96 + q];
    float ov = opart[d * 32 + q] + opart[2048 + d * 32 + q] +
               opart[4096 + d * 32 + q] + opart[6144 + d * 32 + q];
    out[(size_t)(hh * NN + q0 + q) * DOUT + d] = ov / s;
  }
}

extern "C" void kernel_launch(void* const* d_in, const int* in_sizes, int n_in,
                              void* d_out, int out_size, void* d_ws, size_t ws_size,
                              hipStream_t stream) {
  const float* adj = (const float*)d_in[0];
  const float* h   = (const float*)d_in[1];
  const float* WQ  = (const float*)d_in[2];
  const float* bQ  = (const float*)d_in[3];
  const float* WK  = (const float*)d_in[4];
  const float* bK  = (const float*)d_in[5];
  const float* WV  = (const float*)d_in[6];
  const float* bV  = (const float*)d_in[7];
  float* out = (float*)d_out;

  if (ws_size < 12976128) return;  // need ~12.4 MB scratch

  char* ws = (char*)d_ws;
  bf16_t* hb = (bf16_t*)ws;                 // [N][256] bf16            3,145,728 B
  bf16_t* Wt = (bf16_t*)(ws + 3145728);     // [3][H][64][256] bf16       393,216 B
  bf16_t* Qb = (bf16_t*)(ws + 3538944);     // [H][N][64] bf16 (scaled) 3,145,728 B
  bf16_t* Kf = (bf16_t*)(ws + 6684672);     // [H] K fragments          3,145,728 B
  bf16_t* Vf = (bf16_t*)(ws + 9830400);     // [H] V fragments          3,145,728 B

  prep_kernel<<<1024, 256, 0, stream>>>(h, WQ, WK, WV, hb, Wt);
  proj_kernel<<<dim3(96, 4), 256, 0, stream>>>(hb, Wt, bQ, bK, bV, Qb, Kf, Vf);
  attn_kernel<<<dim3(192, 4), 256, 0, stream>>>(adj, Qb, Kf, Vf, out);
}